// Round 4
// baseline (364.180 us; speedup 1.0000x reference)
//
#include <hip/hip_runtime.h>
#include <hip/hip_bf16.h>
#include <cstdint>
#include <cstddef>

// Problem: B=4, S=2048, D=768, H=12, HD=64. out = Attn(RoPE(QKV(x))) @ Wo^T
#define B_ 4
#define S_ 2048
#define D_ 768
#define H_ 12
#define M_ 8192   // B*S
#define KD 768

typedef unsigned short u16;
typedef __attribute__((ext_vector_type(8))) short short8;   // 8 bf16 (4 VGPR) MFMA frag
typedef __attribute__((ext_vector_type(4))) short short4v;  // 4 bf16 (8B store)
typedef __attribute__((ext_vector_type(4))) float f32x4;    // MFMA acc

static __device__ __forceinline__ u16 f2bf(float f) {
  union { float f; unsigned u; } x; x.f = f;
  unsigned r = x.u + 0x7fffu + ((x.u >> 16) & 1u);   // RNE
  return (u16)(r >> 16);
}

// packed f32x2 -> bf16x2 (gfx950 hw cvt, RNE); lo=src0, hi=src1
static __device__ __forceinline__ unsigned cvtpk_bf16(float lo, float hi) {
  unsigned r;
  asm("v_cvt_pk_bf16_f32 %0, %1, %2" : "=v"(r) : "v"(lo), "v"(hi));
  return r;
}

static __device__ __forceinline__ void gload_lds16(const void* g, void* l) {
  __builtin_amdgcn_global_load_lds(
      (const __attribute__((address_space(1))) unsigned int*)g,
      (__attribute__((address_space(3))) unsigned int*)l,
      16, 0, 0);
}

// ---------------- fp32 -> bf16 conversion (8 elems/thread) ----------------
__global__ __launch_bounds__(256) void cvt_kernel(const float* __restrict__ src,
                                                  u16* __restrict__ dst, int n8) {
  int i = blockIdx.x * 256 + threadIdx.x;
  if (i >= n8) return;
  const float4* s4p = (const float4*)src;
  float4 a = s4p[2 * i], b = s4p[2 * i + 1];
  short8 o;
  o[0] = (short)f2bf(a.x); o[1] = (short)f2bf(a.y);
  o[2] = (short)f2bf(a.z); o[3] = (short)f2bf(a.w);
  o[4] = (short)f2bf(b.x); o[5] = (short)f2bf(b.y);
  o[6] = (short)f2bf(b.z); o[7] = (short)f2bf(b.w);
  *(short8*)(dst + (size_t)i * 8) = o;
}

// all 4 weight matrices in one launch (blockIdx.y selects)
__global__ __launch_bounds__(256) void cvtw_kernel(const float* __restrict__ w0,
                                                   const float* __restrict__ w1,
                                                   const float* __restrict__ w2,
                                                   const float* __restrict__ w3,
                                                   u16* __restrict__ dst) {
  int z = blockIdx.y;
  const float* src = (z == 0) ? w0 : (z == 1) ? w1 : (z == 2) ? w2 : w3;
  int i = blockIdx.x * 256 + threadIdx.x;  // < D*D/8
  const float4* s4p = (const float4*)src;
  float4 a = s4p[2 * i], b = s4p[2 * i + 1];
  short8 o;
  o[0] = (short)f2bf(a.x); o[1] = (short)f2bf(a.y);
  o[2] = (short)f2bf(a.z); o[3] = (short)f2bf(a.w);
  o[4] = (short)f2bf(b.x); o[5] = (short)f2bf(b.y);
  o[6] = (short)f2bf(b.z); o[7] = (short)f2bf(b.w);
  *(short8*)(dst + (size_t)z * D_ * D_ + (size_t)i * 8) = o;
}

// ---------------- RoPE cos/sin table: [M_][32] each ----------------
__global__ __launch_bounds__(256) void rope_table_kernel(const int* __restrict__ pos,
                                                         float* __restrict__ cost,
                                                         float* __restrict__ sint) {
  int idx = blockIdx.x * 256 + threadIdx.x;  // < M_*32
  int j = idx & 31, ms = idx >> 5;
  float inv = exp2f(-(float)j * (13.287712379549449f / 32.0f));
  float th = (float)pos[ms] * inv;
  float s, c;
  sincosf(th, &s, &c);
  cost[idx] = c; sint[idx] = s;
}

// ---------------- QKV projection GEMM + bias + RoPE epilogue ----------------
__global__ __launch_bounds__(256, 2) void qkv_gemm_kernel(
    const u16* __restrict__ xbf, const u16* __restrict__ wbf,
    const float* __restrict__ bqp, const float* __restrict__ bkp, const float* __restrict__ bvp,
    const float* __restrict__ cost, const float* __restrict__ sint,
    u16* __restrict__ qbuf, u16* __restrict__ kbuf, u16* __restrict__ vtbuf) {
  __shared__ u16 lA[2][128][32];
  __shared__ u16 lB[2][128][32];
  const int z = blockIdx.z;
  const u16* wz = wbf + (size_t)z * (D_ * D_);
  const float* bias = (z == 0) ? bqp : (z == 1 ? bkp : bvp);
  const int m0 = blockIdx.y * 128;
  const int n0 = blockIdx.x * 128;
  const int t = threadIdx.x;
  const int lane = t & 63, l4 = lane >> 4, l15 = lane & 15;
  const int w = t >> 6, wm = w >> 1, wn = w & 1;

  f32x4 acc[4][4];
#pragma unroll
  for (int m = 0; m < 4; m++)
#pragma unroll
    for (int n = 0; n < 4; n++) acc[m][n] = (f32x4){0.f, 0.f, 0.f, 0.f};

  auto stage = [&](int buf, int k0) {
#pragma unroll
    for (int i = 0; i < 2; i++) {
      int slot = t + 256 * i;
      int row = slot >> 2;
      int s4 = (slot & 3) ^ ((row >> 1) & 3);
      gload_lds16(xbf + (size_t)(m0 + row) * KD + k0 + s4 * 8, &lA[buf][0][0] + slot * 8);
    }
#pragma unroll
    for (int i = 0; i < 2; i++) {
      int slot = t + 256 * i;
      int row = slot >> 2;
      int s4 = (slot & 3) ^ ((row >> 1) & 3);
      gload_lds16(wz + (size_t)(n0 + row) * KD + k0 + s4 * 8, &lB[buf][0][0] + slot * 8);
    }
  };

  stage(0, 0);
  int cur = 0;
  for (int kt = 0; kt < KD / 32; ++kt) {
    __syncthreads();
    if (kt + 1 < KD / 32) stage(cur ^ 1, (kt + 1) * 32);
    short8 af[4], bf[4];
#pragma unroll
    for (int m = 0; m < 4; m++) {
      int row = wm * 64 + m * 16 + l15;
      int s4 = l4 ^ ((row >> 1) & 3);
      af[m] = *(const short8*)(&lA[cur][row][s4 * 8]);
    }
#pragma unroll
    for (int n = 0; n < 4; n++) {
      int row = wn * 64 + n * 16 + l15;
      int s4 = l4 ^ ((row >> 1) & 3);
      bf[n] = *(const short8*)(&lB[cur][row][s4 * 8]);
    }
    __builtin_amdgcn_s_setprio(1);
#pragma unroll
    for (int m = 0; m < 4; m++)
#pragma unroll
      for (int n = 0; n < 4; n++)
        acc[m][n] = __builtin_amdgcn_mfma_f32_16x16x32_bf16(af[m], bf[n], acc[m][n], 0, 0, 0);
    __builtin_amdgcn_s_setprio(0);
    cur ^= 1;
  }

  const int mg_base = m0 + wm * 64;
  const int ng_base = n0 + wn * 64;          // multiple of 64 -> single head per wave
  const int h = ng_base >> 6;
  float bn[4];
#pragma unroll
  for (int n = 0; n < 4; n++) bn[n] = bias[ng_base + n * 16 + l15];

  if (z <= 1) {
    // Q gets 1/sqrt(HD) * log2(e) folded in (softmax uses exp2)
    const float scale = (z == 0) ? 0.18033688011112042f : 1.0f;
    u16* dst = (z == 0) ? qbuf : kbuf;
#pragma unroll
    for (int m = 0; m < 4; m++) {
#pragma unroll
      for (int r = 0; r < 4; r++) {
        int mg = mg_base + m * 16 + (l4 << 2) + r;  // global row = b*S+s
        float c0 = cost[mg * 32 + l15],      s0 = sint[mg * 32 + l15];
        float c1 = cost[mg * 32 + 16 + l15], s1 = sint[mg * 32 + 16 + l15];
        float a0 = acc[m][0][r] + bn[0];
        float a1 = acc[m][1][r] + bn[1];
        float a2 = acc[m][2][r] + bn[2];
        float a3 = acc[m][3][r] + bn[3];
        float o0 = a0 * c0 - a2 * s0;
        float o1 = a1 * c1 - a3 * s1;
        float o2 = a2 * c0 + a0 * s0;
        float o3 = a3 * c1 + a1 * s1;
        int bb = mg >> 11, ss = mg & (S_ - 1);
        size_t rowoff = ((size_t)(bb * H_ + h) * S_ + ss) * 64;
        dst[rowoff + l15]      = f2bf(o0 * scale);
        dst[rowoff + 16 + l15] = f2bf(o1 * scale);
        dst[rowoff + 32 + l15] = f2bf(o2 * scale);
        dst[rowoff + 48 + l15] = f2bf(o3 * scale);
      }
    }
  } else {
    // V: store transposed [BH][64][S] so PV B-frags are contiguous along kv.
#pragma unroll
    for (int m = 0; m < 4; m++) {
      int mgb = mg_base + m * 16 + (l4 << 2);
      int bb = mgb >> 11, ss = mgb & (S_ - 1);
#pragma unroll
      for (int n = 0; n < 4; n++) {
        int hd = n * 16 + l15;
        short4v o;
#pragma unroll
        for (int r = 0; r < 4; r++) o[r] = (short)f2bf(acc[m][n][r] + bn[n]);
        *(short4v*)(vtbuf + ((size_t)(bb * H_ + h) * 64 + hd) * S_ + ss) = o;
      }
    }
  }
}

// ---------------- flash attention ----------------
// grid (bh=48, qtile=16): all 16 q-tiles of a head share an XCD (48%8==0).
// K: LDS double-buffered (issue-early, 1 barrier/tile). V: direct global->reg.
// Row-sum of P comes free from an extra PV MFMA against an all-ones B-frag
// (C-rows = q = l4*4+r match lrun layout) -> no sum shuffles.
__global__ __launch_bounds__(256, 3) void attn_kernel(const u16* __restrict__ qbuf,
                                                      const u16* __restrict__ kbuf,
                                                      const u16* __restrict__ vtbuf,
                                                      u16* __restrict__ abuf) {
  __shared__ u16 kt_[2][64][64];   // dbuf K [kv][hd], 16B-slot swizzle ^ (row&7)
  __shared__ u16 p_[4][32][64];    // per-wave P transpose buffer
  const int bh = blockIdx.x;
  const int b = bh / H_, h = bh % H_;
  const int t = threadIdx.x, lane = t & 63, l4 = lane >> 4, l15 = lane & 15;
  const int w = t >> 6;
  const int q0 = blockIdx.y * 128 + w * 32;  // wave-local 32 q rows
  const u16* qb = qbuf + (size_t)bh * S_ * 64;
  const u16* kb = kbuf + (size_t)bh * S_ * 64;
  const u16* vb = vtbuf + (size_t)bh * 64 * S_;

  short8 qf[2][2];
#pragma unroll
  for (int mq = 0; mq < 2; mq++)
#pragma unroll
    for (int ks = 0; ks < 2; ks++)
      qf[mq][ks] = *(const short8*)(qb + (size_t)(q0 + mq * 16 + l15) * 64 + l4 * 8 + ks * 32);

  short8 ones;
#pragma unroll
  for (int i = 0; i < 8; i++) ones[i] = (short)0x3F80;  // bf16 1.0

  short8 vf[4][2];
  auto loadV = [&](int kv0) {
#pragma unroll
    for (int n = 0; n < 4; n++)
#pragma unroll
      for (int ks = 0; ks < 2; ks++)
        vf[n][ks] = *(const short8*)(vb + (size_t)(n * 16 + l15) * S_ + kv0 + (l4 + 4 * ks) * 8);
  };

  auto stageK = [&](int buf, int kv0) {
#pragma unroll
    for (int i = 0; i < 2; i++) {
      int slot = t + 256 * i;
      int row = slot >> 3;
      int s8 = (slot & 7) ^ (row & 7);
      gload_lds16(kb + (size_t)(kv0 + row) * 64 + s8 * 8, &kt_[buf][0][0] + slot * 8);
    }
  };

  f32x4 oacc[2][4];
  float mrun[2][4], lrun[2][4];
#pragma unroll
  for (int mq = 0; mq < 2; mq++)
#pragma unroll
    for (int n = 0; n < 4; n++) oacc[mq][n] = (f32x4){0.f, 0.f, 0.f, 0.f};
#pragma unroll
  for (int mq = 0; mq < 2; mq++)
#pragma unroll
    for (int r = 0; r < 4; r++) { mrun[mq][r] = -3.0e38f; lrun[mq][r] = 0.f; }

  stageK(0, 0);
  loadV(0);
  __syncthreads();  // K(0) staged (drain)

  const int NT = S_ / 64;
  for (int t_ = 0; t_ < NT; ++t_) {
    const int kv0 = t_ * 64, buf = t_ & 1;
    if (t_ > 0) loadV(kv0);                       // V(t) flies under QK+softmax
    if (t_ + 1 < NT) stageK(buf ^ 1, kv0 + 64);   // K(t+1) flies until end barrier

    // ---- QK^T (q pre-scaled by log2e/8; scores in log2 units) ----
    short8 bkf[4][2];
#pragma unroll
    for (int n = 0; n < 4; n++)
#pragma unroll
      for (int ks = 0; ks < 2; ks++) {
        int row = n * 16 + l15;
        int s8 = (l4 + ks * 4) ^ (row & 7);
        bkf[n][ks] = *(const short8*)(&kt_[buf][0][0] + row * 64 + s8 * 8);
      }
    f32x4 sacc[2][4];
#pragma unroll
    for (int mq = 0; mq < 2; mq++)
#pragma unroll
      for (int n = 0; n < 4; n++) sacc[mq][n] = (f32x4){0.f, 0.f, 0.f, 0.f};
    __builtin_amdgcn_s_setprio(1);
#pragma unroll
    for (int mq = 0; mq < 2; mq++)
#pragma unroll
      for (int n = 0; n < 4; n++)
#pragma unroll
        for (int ks = 0; ks < 2; ks++)
          sacc[mq][n] = __builtin_amdgcn_mfma_f32_16x16x32_bf16(qf[mq][ks], bkf[n][ks], sacc[mq][n], 0, 0, 0);
    __builtin_amdgcn_s_setprio(0);

    // ---- online softmax (log2 units), defer-max THR=11 ----
    float mxv[2][4];
    bool okall = true;
#pragma unroll
    for (int mq = 0; mq < 2; mq++)
#pragma unroll
      for (int r = 0; r < 4; r++) {
        float mx = fmaxf(fmaxf(sacc[mq][0][r], sacc[mq][1][r]), fmaxf(sacc[mq][2][r], sacc[mq][3][r]));
        mx = fmaxf(mx, __shfl_xor(mx, 1));
        mx = fmaxf(mx, __shfl_xor(mx, 2));
        mx = fmaxf(mx, __shfl_xor(mx, 4));
        mx = fmaxf(mx, __shfl_xor(mx, 8));
        mxv[mq][r] = mx;
        okall &= (mx <= mrun[mq][r] + 11.0f);
      }
    if (!__all((int)okall)) {
#pragma unroll
      for (int mq = 0; mq < 2; mq++)
#pragma unroll
        for (int r = 0; r < 4; r++) {
          float nm = fmaxf(mrun[mq][r], mxv[mq][r]);
          float al = exp2f(mrun[mq][r] - nm);
          lrun[mq][r] *= al;
          mrun[mq][r] = nm;
#pragma unroll
          for (int n = 0; n < 4; n++) oacc[mq][n][r] *= al;
        }
    }
#pragma unroll
    for (int mq = 0; mq < 2; mq++)
#pragma unroll
      for (int n = 0; n < 4; n++)
#pragma unroll
        for (int r = 0; r < 4; r++)
          sacc[mq][n][r] = exp2f(sacc[mq][n][r] - mrun[mq][r]);

    // ---- P -> per-wave LDS (transpose to A-frag layout), hw cvt_pk ----
    char* pw = (char*)&p_[w][0][0];
#pragma unroll
    for (int mq = 0; mq < 2; mq++)
#pragma unroll
      for (int n = 0; n < 4; n++) {
        int kvc = n * 16 + l15;
#pragma unroll
        for (int rp = 0; rp < 2; rp++) {
          unsigned pk = cvtpk_bf16(sacc[mq][n][2 * rp], sacc[mq][n][2 * rp + 1]);
          int qr0 = mq * 16 + l4 * 4 + 2 * rp;
          int by0 = (qr0 * 128 + kvc * 2) ^ ((qr0 & 7) << 4);
          int by1 = ((qr0 + 1) * 128 + kvc * 2) ^ (((qr0 + 1) & 7) << 4);
          *(u16*)(pw + by0) = (u16)pk;
          *(u16*)(pw + by1) = (u16)(pk >> 16);
        }
      }

    short8 pa[2][2];
#pragma unroll
    for (int mq = 0; mq < 2; mq++)
#pragma unroll
      for (int ks = 0; ks < 2; ks++) {
        int qr = mq * 16 + l15;
        int s8 = (l4 + ks * 4) ^ (qr & 7);
        pa[mq][ks] = *(const short8*)(pw + qr * 128 + s8 * 16);
      }
    // PV + row-sum via ones-MFMA (lsum rows = q = l4*4+r, matches lrun)
    f32x4 lacc[2];
#pragma unroll
    for (int mq = 0; mq < 2; mq++) lacc[mq] = (f32x4){0.f, 0.f, 0.f, 0.f};
    __builtin_amdgcn_s_setprio(1);
#pragma unroll
    for (int mq = 0; mq < 2; mq++) {
#pragma unroll
      for (int n = 0; n < 4; n++)
#pragma unroll
        for (int ks = 0; ks < 2; ks++)
          oacc[mq][n] = __builtin_amdgcn_mfma_f32_16x16x32_bf16(pa[mq][ks], vf[n][ks], oacc[mq][n], 0, 0, 0);
#pragma unroll
      for (int ks = 0; ks < 2; ks++)
        lacc[mq] = __builtin_amdgcn_mfma_f32_16x16x32_bf16(pa[mq][ks], ones, lacc[mq], 0, 0, 0);
    }
    __builtin_amdgcn_s_setprio(0);
#pragma unroll
    for (int mq = 0; mq < 2; mq++)
#pragma unroll
      for (int r = 0; r < 4; r++) lrun[mq][r] += lacc[mq][r];

    __syncthreads();  // drains vmcnt (K(t+1) landed) + kt_ reuse safety
  }

  // epilogue: O / l, write bf16 [B][S][D]
#pragma unroll
  for (int mq = 0; mq < 2; mq++)
#pragma unroll
    for (int r = 0; r < 4; r++) {
      float inv = 1.0f / lrun[mq][r];
      int s = q0 + mq * 16 + l4 * 4 + r;
#pragma unroll
      for (int n = 0; n < 4; n++) {
        int dcol = h * 64 + n * 16 + l15;
        abuf[(size_t)(b * S_ + s) * D_ + dcol] = f2bf(oacc[mq][n][r] * inv);
      }
    }
}

// ---------------- output projection: out = A @ Wo^T (fp32 out) ----------------
__global__ __launch_bounds__(256, 2) void out_gemm_kernel(const u16* __restrict__ abuf,
                                                          const u16* __restrict__ wobf,
                                                          float* __restrict__ out) {
  __shared__ u16 lA[2][128][32];
  __shared__ u16 lB[2][128][32];
  const int m0 = blockIdx.y * 128;
  const int n0 = blockIdx.x * 128;
  const int t = threadIdx.x;
  const int lane = t & 63, l4 = lane >> 4, l15 = lane & 15;
  const int w = t >> 6, wm = w >> 1, wn = w & 1;

  f32x4 acc[4][4];
#pragma unroll
  for (int m = 0; m < 4; m++)
#pragma unroll
    for (int n = 0; n < 4; n++) acc[m][n] = (f32x4){0.f, 0.f, 0.f, 0.f};

  auto stage = [&](int buf, int k0) {
#pragma unroll
    for (int i = 0; i < 2; i++) {
      int slot = t + 256 * i;
      int row = slot >> 2;
      int s4 = (slot & 3) ^ ((row >> 1) & 3);
      gload_lds16(abuf + (size_t)(m0 + row) * KD + k0 + s4 * 8, &lA[buf][0][0] + slot * 8);
    }
#pragma unroll
    for (int i = 0; i < 2; i++) {
      int slot = t + 256 * i;
      int row = slot >> 2;
      int s4 = (slot & 3) ^ ((row >> 1) & 3);
      gload_lds16(wobf + (size_t)(n0 + row) * KD + k0 + s4 * 8, &lB[buf][0][0] + slot * 8);
    }
  };

  stage(0, 0);
  int cur = 0;
  for (int kt = 0; kt < KD / 32; ++kt) {
    __syncthreads();
    if (kt + 1 < KD / 32) stage(cur ^ 1, (kt + 1) * 32);
    short8 af[4], bf[4];
#pragma unroll
    for (int m = 0; m < 4; m++) {
      int row = wm * 64 + m * 16 + l15;
      int s4 = l4 ^ ((row >> 1) & 3);
      af[m] = *(const short8*)(&lA[cur][row][s4 * 8]);
    }
#pragma unroll
    for (int n = 0; n < 4; n++) {
      int row = wn * 64 + n * 16 + l15;
      int s4 = l4 ^ ((row >> 1) & 3);
      bf[n] = *(const short8*)(&lB[cur][row][s4 * 8]);
    }
    __builtin_amdgcn_s_setprio(1);
#pragma unroll
    for (int m = 0; m < 4; m++)
#pragma unroll
      for (int n = 0; n < 4; n++)
        acc[m][n] = __builtin_amdgcn_mfma_f32_16x16x32_bf16(af[m], bf[n], acc[m][n], 0, 0, 0);
    __builtin_amdgcn_s_setprio(0);
    cur ^= 1;
  }

  const int mg_base = m0 + wm * 64;
  const int ng_base = n0 + wn * 64;
#pragma unroll
  for (int m = 0; m < 4; m++)
#pragma unroll
    for (int r = 0; r < 4; r++) {
      int mg = mg_base + m * 16 + (l4 << 2) + r;
      size_t rb = (size_t)mg * D_ + ng_base + l15;
      out[rb]      = acc[m][0][r];
      out[rb + 16] = acc[m][1][r];
      out[rb + 32] = acc[m][2][r];
      out[rb + 48] = acc[m][3][r];
    }
}

// ---------------- launcher ----------------
extern "C" void kernel_launch(void* const* d_in, const int* in_sizes, int n_in,
                              void* d_out, int out_size, void* d_ws, size_t ws_size,
                              hipStream_t stream) {
  const float* hs  = (const float*)d_in[0];
  const int*   pos = (const int*)d_in[1];
  const float* wq  = (const float*)d_in[2];
  const float* bq  = (const float*)d_in[3];
  const float* wk  = (const float*)d_in[4];
  const float* bk  = (const float*)d_in[5];
  const float* wv  = (const float*)d_in[6];
  const float* bv  = (const float*)d_in[7];
  const float* wo  = (const float*)d_in[8];
  float* out = (float*)d_out;

  // workspace layout (bf16 as u16)
  u16* xbf   = (u16*)d_ws;                 // 8192*768
  u16* wbf   = xbf + (size_t)M_ * D_;      // 4 * 768*768 (q,k,v,o)
  u16* qbuf  = wbf + (size_t)4 * D_ * D_;  // [48][2048][64]
  u16* kbuf  = qbuf + (size_t)M_ * D_;     // [48][2048][64]
  u16* vtbuf = kbuf + (size_t)M_ * D_;     // [48][64][2048]
  u16* abuf  = vtbuf + (size_t)M_ * D_;    // [8192][768]
  float* cost = (float*)(abuf + (size_t)M_ * D_);
  float* sint = cost + (size_t)M_ * 32;

  // 1) convert X and weights to bf16
  cvt_kernel<<<dim3((M_ * D_ / 8 + 255) / 256), dim3(256), 0, stream>>>(hs, xbf, M_ * D_ / 8);
  cvtw_kernel<<<dim3(D_ * D_ / 8 / 256, 4), dim3(256), 0, stream>>>(wq, wk, wv, wo, wbf);

  // 2) RoPE table
  rope_table_kernel<<<dim3(M_ * 32 / 256), dim3(256), 0, stream>>>(pos, cost, sint);

  // 3) QKV projection + bias + RoPE (+log2e/8 scale on Q), V stored transposed
  qkv_gemm_kernel<<<dim3(D_ / 128, M_ / 128, 3), dim3(256), 0, stream>>>(
      xbf, wbf, bq, bk, bv, cost, sint, qbuf, kbuf, vtbuf);

  // 4) flash attention (grid: bh fast -> head-per-XCD L2 locality)
  attn_kernel<<<dim3(B_ * H_, S_ / 128), dim3(256), 0, stream>>>(qbuf, kbuf, vtbuf, abuf);

  // 5) output projection
  out_gemm_kernel<<<dim3(D_ / 128, M_ / 128), dim3(256), 0, stream>>>(abuf, wbf + (size_t)3 * D_ * D_, out);
}

// Round 5
// 268.488 us; speedup vs baseline: 1.3564x; 1.3564x over previous
//
#include <hip/hip_runtime.h>
#include <hip/hip_bf16.h>
#include <cstdint>
#include <cstddef>

// Problem: B=4, S=2048, D=768, H=12, HD=64. out = Attn(RoPE(QKV(x))) @ Wo^T
#define B_ 4
#define S_ 2048
#define D_ 768
#define H_ 12
#define M_ 8192   // B*S
#define KD 768

typedef unsigned short u16;
typedef __attribute__((ext_vector_type(8))) short short8;   // 8 bf16 (4 VGPR) MFMA frag
typedef __attribute__((ext_vector_type(4))) short short4v;  // 4 bf16 (8B store)
typedef __attribute__((ext_vector_type(4))) float f32x4;    // 16x16 MFMA acc
typedef __attribute__((ext_vector_type(16))) float f32x16;  // 32x32 MFMA acc

static __device__ __forceinline__ u16 f2bf(float f) {
  union { float f; unsigned u; } x; x.f = f;
  unsigned r = x.u + 0x7fffu + ((x.u >> 16) & 1u);   // RNE
  return (u16)(r >> 16);
}

// packed f32x2 -> bf16x2 (gfx950 hw cvt, RNE); lo=src0, hi=src1
static __device__ __forceinline__ unsigned cvtpk_bf16(float lo, float hi) {
  unsigned r;
  asm("v_cvt_pk_bf16_f32 %0, %1, %2" : "=v"(r) : "v"(lo), "v"(hi));
  return r;
}

static __device__ __forceinline__ void gload_lds16(const void* g, void* l) {
  __builtin_amdgcn_global_load_lds(
      (const __attribute__((address_space(1))) unsigned int*)g,
      (__attribute__((address_space(3))) unsigned int*)l,
      16, 0, 0);
}

// ---------------- fp32 -> bf16 conversion (8 elems/thread) ----------------
__global__ __launch_bounds__(256) void cvt_kernel(const float* __restrict__ src,
                                                  u16* __restrict__ dst, int n8) {
  int i = blockIdx.x * 256 + threadIdx.x;
  if (i >= n8) return;
  const float4* s4p = (const float4*)src;
  float4 a = s4p[2 * i], b = s4p[2 * i + 1];
  short8 o;
  o[0] = (short)f2bf(a.x); o[1] = (short)f2bf(a.y);
  o[2] = (short)f2bf(a.z); o[3] = (short)f2bf(a.w);
  o[4] = (short)f2bf(b.x); o[5] = (short)f2bf(b.y);
  o[6] = (short)f2bf(b.z); o[7] = (short)f2bf(b.w);
  *(short8*)(dst + (size_t)i * 8) = o;
}

// all 4 weight matrices in one launch (blockIdx.y selects)
__global__ __launch_bounds__(256) void cvtw_kernel(const float* __restrict__ w0,
                                                   const float* __restrict__ w1,
                                                   const float* __restrict__ w2,
                                                   const float* __restrict__ w3,
                                                   u16* __restrict__ dst) {
  int z = blockIdx.y;
  const float* src = (z == 0) ? w0 : (z == 1) ? w1 : (z == 2) ? w2 : w3;
  int i = blockIdx.x * 256 + threadIdx.x;  // < D*D/8
  const float4* s4p = (const float4*)src;
  float4 a = s4p[2 * i], b = s4p[2 * i + 1];
  short8 o;
  o[0] = (short)f2bf(a.x); o[1] = (short)f2bf(a.y);
  o[2] = (short)f2bf(a.z); o[3] = (short)f2bf(a.w);
  o[4] = (short)f2bf(b.x); o[5] = (short)f2bf(b.y);
  o[6] = (short)f2bf(b.z); o[7] = (short)f2bf(b.w);
  *(short8*)(dst + (size_t)z * D_ * D_ + (size_t)i * 8) = o;
}

// ---------------- RoPE cos/sin table: [M_][32] each ----------------
__global__ __launch_bounds__(256) void rope_table_kernel(const int* __restrict__ pos,
                                                         float* __restrict__ cost,
                                                         float* __restrict__ sint) {
  int idx = blockIdx.x * 256 + threadIdx.x;  // < M_*32
  int j = idx & 31, ms = idx >> 5;
  float inv = exp2f(-(float)j * (13.287712379549449f / 32.0f));
  float th = (float)pos[ms] * inv;
  float s, c;
  sincosf(th, &s, &c);
  cost[idx] = c; sint[idx] = s;
}

// ---------------- QKV projection GEMM + bias + RoPE epilogue ----------------
__global__ __launch_bounds__(256, 2) void qkv_gemm_kernel(
    const u16* __restrict__ xbf, const u16* __restrict__ wbf,
    const float* __restrict__ bqp, const float* __restrict__ bkp, const float* __restrict__ bvp,
    const float* __restrict__ cost, const float* __restrict__ sint,
    u16* __restrict__ qbuf, u16* __restrict__ kbuf, u16* __restrict__ vtbuf) {
  __shared__ u16 lA[2][128][32];
  __shared__ u16 lB[2][128][32];
  const int z = blockIdx.z;
  const u16* wz = wbf + (size_t)z * (D_ * D_);
  const float* bias = (z == 0) ? bqp : (z == 1 ? bkp : bvp);
  const int m0 = blockIdx.y * 128;
  const int n0 = blockIdx.x * 128;
  const int t = threadIdx.x;
  const int lane = t & 63, l4 = lane >> 4, l15 = lane & 15;
  const int w = t >> 6, wm = w >> 1, wn = w & 1;

  f32x4 acc[4][4];
#pragma unroll
  for (int m = 0; m < 4; m++)
#pragma unroll
    for (int n = 0; n < 4; n++) acc[m][n] = (f32x4){0.f, 0.f, 0.f, 0.f};

  auto stage = [&](int buf, int k0) {
#pragma unroll
    for (int i = 0; i < 2; i++) {
      int slot = t + 256 * i;
      int row = slot >> 2;
      int s4 = (slot & 3) ^ ((row >> 1) & 3);
      gload_lds16(xbf + (size_t)(m0 + row) * KD + k0 + s4 * 8, &lA[buf][0][0] + slot * 8);
    }
#pragma unroll
    for (int i = 0; i < 2; i++) {
      int slot = t + 256 * i;
      int row = slot >> 2;
      int s4 = (slot & 3) ^ ((row >> 1) & 3);
      gload_lds16(wz + (size_t)(n0 + row) * KD + k0 + s4 * 8, &lB[buf][0][0] + slot * 8);
    }
  };

  stage(0, 0);
  int cur = 0;
  for (int kt = 0; kt < KD / 32; ++kt) {
    __syncthreads();
    if (kt + 1 < KD / 32) stage(cur ^ 1, (kt + 1) * 32);
    short8 af[4], bf[4];
#pragma unroll
    for (int m = 0; m < 4; m++) {
      int row = wm * 64 + m * 16 + l15;
      int s4 = l4 ^ ((row >> 1) & 3);
      af[m] = *(const short8*)(&lA[cur][row][s4 * 8]);
    }
#pragma unroll
    for (int n = 0; n < 4; n++) {
      int row = wn * 64 + n * 16 + l15;
      int s4 = l4 ^ ((row >> 1) & 3);
      bf[n] = *(const short8*)(&lB[cur][row][s4 * 8]);
    }
    __builtin_amdgcn_s_setprio(1);
#pragma unroll
    for (int m = 0; m < 4; m++)
#pragma unroll
      for (int n = 0; n < 4; n++)
        acc[m][n] = __builtin_amdgcn_mfma_f32_16x16x32_bf16(af[m], bf[n], acc[m][n], 0, 0, 0);
    __builtin_amdgcn_s_setprio(0);
    cur ^= 1;
  }

  const int mg_base = m0 + wm * 64;
  const int ng_base = n0 + wn * 64;          // multiple of 64 -> single head per wave
  const int h = ng_base >> 6;
  float bn[4];
#pragma unroll
  for (int n = 0; n < 4; n++) bn[n] = bias[ng_base + n * 16 + l15];

  if (z <= 1) {
    // Q gets 1/sqrt(HD) * log2(e) folded in (softmax uses exp2)
    const float scale = (z == 0) ? 0.18033688011112042f : 1.0f;
    u16* dst = (z == 0) ? qbuf : kbuf;
#pragma unroll
    for (int m = 0; m < 4; m++) {
#pragma unroll
      for (int r = 0; r < 4; r++) {
        int mg = mg_base + m * 16 + (l4 << 2) + r;  // global row = b*S+s
        float c0 = cost[mg * 32 + l15],      s0 = sint[mg * 32 + l15];
        float c1 = cost[mg * 32 + 16 + l15], s1 = sint[mg * 32 + 16 + l15];
        float a0 = acc[m][0][r] + bn[0];
        float a1 = acc[m][1][r] + bn[1];
        float a2 = acc[m][2][r] + bn[2];
        float a3 = acc[m][3][r] + bn[3];
        float o0 = a0 * c0 - a2 * s0;
        float o1 = a1 * c1 - a3 * s1;
        float o2 = a2 * c0 + a0 * s0;
        float o3 = a3 * c1 + a1 * s1;
        int bb = mg >> 11, ss = mg & (S_ - 1);
        size_t rowoff = ((size_t)(bb * H_ + h) * S_ + ss) * 64;
        dst[rowoff + l15]      = f2bf(o0 * scale);
        dst[rowoff + 16 + l15] = f2bf(o1 * scale);
        dst[rowoff + 32 + l15] = f2bf(o2 * scale);
        dst[rowoff + 48 + l15] = f2bf(o3 * scale);
      }
    }
  } else {
    // V: store transposed [BH][64][S] so PV A-frags are contiguous along kv.
#pragma unroll
    for (int m = 0; m < 4; m++) {
      int mgb = mg_base + m * 16 + (l4 << 2);
      int bb = mgb >> 11, ss = mgb & (S_ - 1);
#pragma unroll
      for (int n = 0; n < 4; n++) {
        int hd = n * 16 + l15;
        short4v o;
#pragma unroll
        for (int r = 0; r < 4; r++) o[r] = (short)f2bf(acc[m][n][r] + bn[n]);
        *(short4v*)(vtbuf + ((size_t)(bb * H_ + h) * 64 + hd) * S_ + ss) = o;
      }
    }
  }
}

// ---------------- flash attention v2: swapped-operand 32x32 MFMA ----------------
// Per wave: 32 q rows. S^T = mfma(A=K, B=Q): lane owns q = lane&31 (C col),
// kv = (reg&3)+8*(reg>>2)+4*(lane>>5). Softmax is lane-local + one shfl_xor(32).
// P^T feeds PV's B operand in-register (cvt_pk + shfl_xor(32) + half-select);
// O^T = mfma(A=V^T, B=P^T) keeps col=q so m/l/alpha stay per-lane scalars.
__global__ __launch_bounds__(256, 4) void attn_kernel(const u16* __restrict__ qbuf,
                                                      const u16* __restrict__ kbuf,
                                                      const u16* __restrict__ vtbuf,
                                                      u16* __restrict__ abuf) {
  __shared__ u16 kt_[2][64][64];   // dbuf K [kv][hd], 16B-slot swizzle ^ (row&7)
  const int bh = blockIdx.x;
  const int b = bh / H_, h = bh % H_;
  const int t = threadIdx.x, lane = t & 63;
  const int w = t >> 6;
  const int l31 = lane & 31, hi = lane >> 5;
  const int q = blockIdx.y * 128 + w * 32 + l31;  // this lane's q column
  const u16* qb = qbuf + (size_t)bh * S_ * 64;
  const u16* kb = kbuf + (size_t)bh * S_ * 64;
  const u16* vb = vtbuf + (size_t)bh * 64 * S_;

  // Q as QK^T B-operand: B[k=d][q]: lane reads Q[q][ks*16 + hi*8 .. +8]
  short8 qf[4];
#pragma unroll
  for (int ks = 0; ks < 4; ks++)
    qf[ks] = *(const short8*)(qb + (size_t)q * 64 + ks * 16 + hi * 8);

  f32x16 oacc[2];
#pragma unroll
  for (int r = 0; r < 16; r++) { oacc[0][r] = 0.f; oacc[1][r] = 0.f; }
  float mrun = -3.0e38f, lrun = 0.f;

  auto stageK = [&](int buf, int kv0) {
#pragma unroll
    for (int i = 0; i < 2; i++) {
      int slot = t + 256 * i;
      int row = slot >> 3;
      int s8 = (slot & 7) ^ (row & 7);
      gload_lds16(kb + (size_t)(kv0 + row) * 64 + s8 * 8, &kt_[buf][0][0] + slot * 8);
    }
  };

  stageK(0, 0);
  __syncthreads();

  const int NT = S_ / 64;
  for (int t_ = 0; t_ < NT; ++t_) {
    const int kv0 = t_ * 64, buf = t_ & 1;
    if (t_ + 1 < NT) stageK(buf ^ 1, kv0 + 64);  // flies until end barrier

#pragma unroll
    for (int sub = 0; sub < 2; ++sub) {
      const int kvs = sub * 32;
      // V^T A-frags (global; identical addrs across waves -> L1 broadcast)
      short8 vf[2][2];
#pragma unroll
      for (int hh = 0; hh < 2; hh++)
#pragma unroll
        for (int kt2 = 0; kt2 < 2; kt2++)
          vf[hh][kt2] = *(const short8*)(vb + (size_t)(hh * 32 + l31) * S_ +
                                         kv0 + kvs + kt2 * 16 + hi * 8);

      // ---- QK^T: S^T[kv][q], 4 k-steps over d ----
      f32x16 sacc;
#pragma unroll
      for (int r = 0; r < 16; r++) sacc[r] = 0.f;
      const char* kbase = (const char*)&kt_[buf][0][0];
      __builtin_amdgcn_s_setprio(1);
#pragma unroll
      for (int ks = 0; ks < 4; ks++) {
        int row = kvs + l31;
        int byte = ((ks * 2 + hi) * 16) ^ ((row & 7) << 4);
        short8 kf = *(const short8*)(kbase + row * 128 + byte);
        sacc = __builtin_amdgcn_mfma_f32_32x32x16_bf16(kf, qf[ks], sacc, 0, 0, 0);
      }
      __builtin_amdgcn_s_setprio(0);

      // ---- softmax (log2 units), lane-local + one cross-half swap ----
      float mx = sacc[0];
#pragma unroll
      for (int r = 1; r < 16; r++) mx = fmaxf(mx, sacc[r]);
      mx = fmaxf(mx, __shfl_xor(mx, 32));
      bool ok = (mx <= mrun + 11.0f);     // defer-max THR (log2 units)
      if (!__all((int)ok)) {
        float nm = fmaxf(mrun, mx);
        float al = exp2f(mrun - nm);
        lrun *= al;
#pragma unroll
        for (int r = 0; r < 16; r++) { oacc[0][r] *= al; oacc[1][r] *= al; }
        mrun = nm;
      }
      float p[16];
      float ls = 0.f;
#pragma unroll
      for (int r = 0; r < 16; r++) { p[r] = exp2f(sacc[r] - mrun); ls += p[r]; }
      ls += __shfl_xor(ls, 32);
      lrun += ls;

      // ---- P^T B-frags in-register (cvt_pk + cross-half exchange) ----
      // lane's p[r] = P[kv=(r&3)+8*(r>>2)+4*hi][q]; B kt: k=(hi*8+e), kv=kt*16+k
      unsigned a0 = cvtpk_bf16(p[0], p[1]),   a1 = cvtpk_bf16(p[2], p[3]);
      unsigned b0 = cvtpk_bf16(p[4], p[5]),   b1 = cvtpk_bf16(p[6], p[7]);
      unsigned c0 = cvtpk_bf16(p[8], p[9]),   c1 = cvtpk_bf16(p[10], p[11]);
      unsigned d0 = cvtpk_bf16(p[12], p[13]), d1 = cvtpk_bf16(p[14], p[15]);
      unsigned xa0 = __shfl_xor(a0, 32), xa1 = __shfl_xor(a1, 32);
      unsigned xb0 = __shfl_xor(b0, 32), xb1 = __shfl_xor(b1, 32);
      unsigned xc0 = __shfl_xor(c0, 32), xc1 = __shfl_xor(c1, 32);
      unsigned xd0 = __shfl_xor(d0, 32), xd1 = __shfl_xor(d1, 32);
      union PW { unsigned w[4]; short8 s; };
      PW pw0, pw1;
      pw0.w[0] = hi ? xb0 : a0;  pw0.w[1] = hi ? xb1 : a1;   // kt=0: kv 0..15
      pw0.w[2] = hi ? b0 : xa0;  pw0.w[3] = hi ? b1 : xa1;
      pw1.w[0] = hi ? xd0 : c0;  pw1.w[1] = hi ? xd1 : c1;   // kt=1: kv 16..31
      pw1.w[2] = hi ? d0 : xc0;  pw1.w[3] = hi ? d1 : xc1;

      // ---- PV: O^T[hd][q] += V^T * P^T ----
      __builtin_amdgcn_s_setprio(1);
      oacc[0] = __builtin_amdgcn_mfma_f32_32x32x16_bf16(vf[0][0], pw0.s, oacc[0], 0, 0, 0);
      oacc[0] = __builtin_amdgcn_mfma_f32_32x32x16_bf16(vf[0][1], pw1.s, oacc[0], 0, 0, 0);
      oacc[1] = __builtin_amdgcn_mfma_f32_32x32x16_bf16(vf[1][0], pw0.s, oacc[1], 0, 0, 0);
      oacc[1] = __builtin_amdgcn_mfma_f32_32x32x16_bf16(vf[1][1], pw1.s, oacc[1], 0, 0, 0);
      __builtin_amdgcn_s_setprio(0);
    }
    __syncthreads();  // drains vmcnt (K(t+1) landed) + kt_ reuse safety
  }

  // epilogue: O^T/l -> abuf[B][S][D]; lane writes its q row, 4B packed pairs
  float inv = 1.0f / lrun;
  u16* orow = abuf + (size_t)(b * S_ + q) * D_ + h * 64;
#pragma unroll
  for (int hh = 0; hh < 2; hh++)
#pragma unroll
    for (int i = 0; i < 8; i++) {
      int hd = ((2 * i) & 3) + 8 * (i >> 1) + 4 * hi + 32 * hh;
      unsigned pk = cvtpk_bf16(oacc[hh][2 * i] * inv, oacc[hh][2 * i + 1] * inv);
      *(unsigned*)(orow + hd) = pk;
    }
}

// ---------------- output projection: out = A @ Wo^T (fp32 out) ----------------
__global__ __launch_bounds__(256, 2) void out_gemm_kernel(const u16* __restrict__ abuf,
                                                          const u16* __restrict__ wobf,
                                                          float* __restrict__ out) {
  __shared__ u16 lA[2][128][32];
  __shared__ u16 lB[2][128][32];
  const int m0 = blockIdx.y * 128;
  const int n0 = blockIdx.x * 128;
  const int t = threadIdx.x;
  const int lane = t & 63, l4 = lane >> 4, l15 = lane & 15;
  const int w = t >> 6, wm = w >> 1, wn = w & 1;

  f32x4 acc[4][4];
#pragma unroll
  for (int m = 0; m < 4; m++)
#pragma unroll
    for (int n = 0; n < 4; n++) acc[m][n] = (f32x4){0.f, 0.f, 0.f, 0.f};

  auto stage = [&](int buf, int k0) {
#pragma unroll
    for (int i = 0; i < 2; i++) {
      int slot = t + 256 * i;
      int row = slot >> 2;
      int s4 = (slot & 3) ^ ((row >> 1) & 3);
      gload_lds16(abuf + (size_t)(m0 + row) * KD + k0 + s4 * 8, &lA[buf][0][0] + slot * 8);
    }
#pragma unroll
    for (int i = 0; i < 2; i++) {
      int slot = t + 256 * i;
      int row = slot >> 2;
      int s4 = (slot & 3) ^ ((row >> 1) & 3);
      gload_lds16(wobf + (size_t)(n0 + row) * KD + k0 + s4 * 8, &lB[buf][0][0] + slot * 8);
    }
  };

  stage(0, 0);
  int cur = 0;
  for (int kt = 0; kt < KD / 32; ++kt) {
    __syncthreads();
    if (kt + 1 < KD / 32) stage(cur ^ 1, (kt + 1) * 32);
    short8 af[4], bf[4];
#pragma unroll
    for (int m = 0; m < 4; m++) {
      int row = wm * 64 + m * 16 + l15;
      int s4 = l4 ^ ((row >> 1) & 3);
      af[m] = *(const short8*)(&lA[cur][row][s4 * 8]);
    }
#pragma unroll
    for (int n = 0; n < 4; n++) {
      int row = wn * 64 + n * 16 + l15;
      int s4 = l4 ^ ((row >> 1) & 3);
      bf[n] = *(const short8*)(&lB[cur][row][s4 * 8]);
    }
    __builtin_amdgcn_s_setprio(1);
#pragma unroll
    for (int m = 0; m < 4; m++)
#pragma unroll
      for (int n = 0; n < 4; n++)
        acc[m][n] = __builtin_amdgcn_mfma_f32_16x16x32_bf16(af[m], bf[n], acc[m][n], 0, 0, 0);
    __builtin_amdgcn_s_setprio(0);
    cur ^= 1;
  }

  const int mg_base = m0 + wm * 64;
  const int ng_base = n0 + wn * 64;
#pragma unroll
  for (int m = 0; m < 4; m++)
#pragma unroll
    for (int r = 0; r < 4; r++) {
      int mg = mg_base + m * 16 + (l4 << 2) + r;
      size_t rb = (size_t)mg * D_ + ng_base + l15;
      out[rb]      = acc[m][0][r];
      out[rb + 16] = acc[m][1][r];
      out[rb + 32] = acc[m][2][r];
      out[rb + 48] = acc[m][3][r];
    }
}

// ---------------- launcher ----------------
extern "C" void kernel_launch(void* const* d_in, const int* in_sizes, int n_in,
                              void* d_out, int out_size, void* d_ws, size_t ws_size,
                              hipStream_t stream) {
  const float* hs  = (const float*)d_in[0];
  const int*   pos = (const int*)d_in[1];
  const float* wq  = (const float*)d_in[2];
  const float* bq  = (const float*)d_in[3];
  const float* wk  = (const float*)d_in[4];
  const float* bk  = (const float*)d_in[5];
  const float* wv  = (const float*)d_in[6];
  const float* bv  = (const float*)d_in[7];
  const float* wo  = (const float*)d_in[8];
  float* out = (float*)d_out;

  // workspace layout (bf16 as u16)
  u16* xbf   = (u16*)d_ws;                 // 8192*768
  u16* wbf   = xbf + (size_t)M_ * D_;      // 4 * 768*768 (q,k,v,o)
  u16* qbuf  = wbf + (size_t)4 * D_ * D_;  // [48][2048][64]
  u16* kbuf  = qbuf + (size_t)M_ * D_;     // [48][2048][64]
  u16* vtbuf = kbuf + (size_t)M_ * D_;     // [48][64][2048]
  u16* abuf  = vtbuf + (size_t)M_ * D_;    // [8192][768]
  float* cost = (float*)(abuf + (size_t)M_ * D_);
  float* sint = cost + (size_t)M_ * 32;

  // 1) convert X and weights to bf16
  cvt_kernel<<<dim3((M_ * D_ / 8 + 255) / 256), dim3(256), 0, stream>>>(hs, xbf, M_ * D_ / 8);
  cvtw_kernel<<<dim3(D_ * D_ / 8 / 256, 4), dim3(256), 0, stream>>>(wq, wk, wv, wo, wbf);

  // 2) RoPE table
  rope_table_kernel<<<dim3(M_ * 32 / 256), dim3(256), 0, stream>>>(pos, cost, sint);

  // 3) QKV projection + bias + RoPE (+log2e/8 scale on Q), V stored transposed
  qkv_gemm_kernel<<<dim3(D_ / 128, M_ / 128, 3), dim3(256), 0, stream>>>(
      xbf, wbf, bq, bk, bv, cost, sint, qbuf, kbuf, vtbuf);

  // 4) flash attention (grid: bh fast -> head-per-XCD L2 locality)
  attn_kernel<<<dim3(B_ * H_, S_ / 128), dim3(256), 0, stream>>>(qbuf, kbuf, vtbuf, abuf);

  // 5) output projection
  out_gemm_kernel<<<dim3(D_ / 128, M_ / 128), dim3(256), 0, stream>>>(abuf, wbf + (size_t)3 * D_ * D_, out);
}